// Round 1
// baseline (111.891 us; speedup 1.0000x reference)
//
#include <hip/hip_runtime.h>

// Problem constants (match reference): B=1024, T=256, C=16, NB=64
// TC = T*C = 4096 (t,c) pairs; x_fake flat index = b*4096 + tc
//
// Kernel 1: one WAVE per (t,c). lane = b-offset; each lane holds 16 x values
// (covering all 1024 b). locs/deltas/densities are wave-uniform -> scalar
// loads. Per bin k: cnt = sum_j popcount(ballot(|x - loc_k| < delta/2)),
// then the loss term accumulates in-wave (uniform). One plain store per wave
// to ws[tc]. Kernel 2: deterministic reduction of 4096 partials -> out[0].

__global__ __launch_bounds__(256) void histo_count_kernel(
    const float* __restrict__ x,       // [1024, 4096]
    const float* __restrict__ locs,    // [4096, 64]
    const float* __restrict__ deltas,  // [4096]
    const float* __restrict__ dens,    // [4096, 64]
    float* __restrict__ ws_partial)    // [4096]
{
    const int lane = threadIdx.x & 63;
    // force wave-uniformity so locs/deltas/dens loads scalarize (s_load)
    const int widx = __builtin_amdgcn_readfirstlane((int)(threadIdx.x >> 6));
    const int tc = blockIdx.x * 4 + widx;   // 0..4095; consecutive waves share t -> L2 line reuse

    // Load this wave's 1024 x values: 16 per lane, stride 4096 floats.
    const float* xp = x + tc;
    float xv[16];
#pragma unroll
    for (int j = 0; j < 16; ++j)
        xv[j] = xp[(size_t)(j * 64 + lane) * 4096u];

    const float delta = deltas[tc];
    const float h   = 0.5f * delta;               // strict: dist < delta/2
    const float inv = 1.0f / (1024.0f * delta);   // density = cnt/(B*delta)
    const float* Lp = locs + tc * 64;
    const float* Dp = dens + tc * 64;

    float lsum = 0.0f;
#pragma unroll 8
    for (int k = 0; k < 64; ++k) {
        const float lk = Lp[k];
        int cnt = 0;
#pragma unroll
        for (int j = 0; j < 16; ++j) {
            // v_sub + v_cmp(abs modifier) -> mask; popcount on scalar pipe
            cnt += __popcll(__ballot(fabsf(xv[j] - lk) < h));
        }
        lsum += fabsf((float)cnt * inv - Dp[k]);
    }

    if (lane == 0)
        ws_partial[tc] = lsum;
}

__global__ __launch_bounds__(256) void histo_reduce_kernel(
    const float* __restrict__ ws_partial,  // [4096]
    float* __restrict__ out)               // [1]
{
    __shared__ float sbuf[4];
    const int tid = threadIdx.x;

    float s = 0.0f;
#pragma unroll
    for (int i = 0; i < 16; ++i)
        s += ws_partial[tid + i * 256];

#pragma unroll
    for (int off = 32; off > 0; off >>= 1)
        s += __shfl_down(s, off, 64);

    if ((tid & 63) == 0) sbuf[tid >> 6] = s;
    __syncthreads();

    if (tid == 0) {
        // REG * mean over (t, c, k): sum / (256*16*64)
        out[0] = (sbuf[0] + sbuf[1] + sbuf[2] + sbuf[3]) * (1.0f / 262144.0f);
    }
}

extern "C" void kernel_launch(void* const* d_in, const int* in_sizes, int n_in,
                              void* d_out, int out_size, void* d_ws, size_t ws_size,
                              hipStream_t stream) {
    const float* x      = (const float*)d_in[0];  // x_fake   [1024,256,16]
    const float* locs   = (const float*)d_in[1];  // locs     [256,16,64]
    const float* deltas = (const float*)d_in[2];  // deltas   [256,16]
    const float* dens   = (const float*)d_in[3];  // densities[256,16,64]
    float* out = (float*)d_out;
    float* wsf = (float*)d_ws;                    // 4096 floats = 16 KiB

    histo_count_kernel<<<1024, 256, 0, stream>>>(x, locs, deltas, dens, wsf);
    histo_reduce_kernel<<<1, 256, 0, stream>>>(wsf, out);
}

// Round 2
// 103.561 us; speedup vs baseline: 1.0804x; 1.0804x over previous
//
#include <hip/hip_runtime.h>

// HistoLoss: B=1024, T=256, C=16, NB=64; TC=T*C=4096; x flat = [b][tc]
//
// k1: block = 128 thr (16 c x 8 kq), one block per (t, 128-b chunk).
//     Stage x[chunk][t][:] in LDS (line-exact: each 64B x-line read by exactly
//     one block -> x fetch == 16 MiB). Per b: 1 LDS broadcast + 8x3 VALU
//     (sub, cmp-abs, addc) per thread. Counts <=128 -> pack 8 x u8 per thread
//     into one 8B store. All accumulation in VALU pipe (round-1 ballot version
//     was SALU-pipe-bound: 2 SALU/indicator on the per-CU scalar unit).
//     Block swizzle: t = bidx & 255, chunk = bidx >> 8 (256 % 8 == 0 keeps all
//     chunks of one t on the same XCD -> locs fetched once per XCD).
// k2: sum 8 chunk partials, loss per (tc,k), block reduce, atomicAdd.
//     k1 block 0 zeroes out[0] (stream-ordered before k2; poison-safe).

#define B_TOT   1024
#define T_DIM   256
#define C_DIM   16
#define NB      64
#define TC      4096
#define CHUNKS  8
#define BCH     128            // b per chunk (counts fit u8)
#define KPT     8              // k per thread

__global__ __launch_bounds__(128) void histo_count_kernel(
    const float* __restrict__ x,       // [1024, 4096]
    const float* __restrict__ locs,    // [4096, 64]
    const float* __restrict__ deltas,  // [4096]
    unsigned char* __restrict__ counts,// [CHUNKS][4096][64] u8
    float* __restrict__ out)           // [1] (zero-init only)
{
    __shared__ float xs[BCH * C_DIM];  // 2048 floats = 8 KB
    const int tid   = threadIdx.x;
    const int t     = blockIdx.x & 255;
    const int chunk = blockIdx.x >> 8;
    const int b0    = chunk * BCH;

    if (blockIdx.x == 0 && tid == 0) out[0] = 0.0f;

    // Stage x[b0..b0+127][t*16 .. t*16+15] -> LDS. float4, fully coalesced:
    // every fetched 64B line is fully consumed, and only by this block.
    const float* xbase = x + (size_t)b0 * TC + t * C_DIM;
#pragma unroll
    for (int p = 0; p < 4; ++p) {
        const int lin = p * 512 + tid * 4;
        const int bi  = lin >> 4;
        const int c4  = lin & 15;
        *(float4*)(xs + lin) = *(const float4*)(xbase + (size_t)bi * TC + c4);
    }

    const int c  = tid >> 3;           // 0..15
    const int kq = tid & 7;            // 0..7 -> k in [kq*8, kq*8+8)
    const int tc = t * C_DIM + c;

    const float h = 0.5f * deltas[tc];
    float lc[KPT];
    const float* lp = locs + (size_t)tc * NB + kq * KPT;
#pragma unroll
    for (int j = 0; j < KPT; ++j) lc[j] = lp[j];

    int cnt[KPT];
#pragma unroll
    for (int j = 0; j < KPT; ++j) cnt[j] = 0;

    __syncthreads();

    // Main loop: LDS broadcast read (8 distinct addrs/wave, 8-lane broadcast
    // each -> conflict-free) + 3 VALU per indicator. Zero SALU in the loop.
    const float* xc = xs + c;
#pragma unroll 8
    for (int bi = 0; bi < BCH; ++bi) {
        const float xv = xc[bi * C_DIM];
#pragma unroll
        for (int j = 0; j < KPT; ++j)
            cnt[j] += (fabsf(xv - lc[j]) < h) ? 1 : 0;
    }

    // Pack 8 u8 counts (<=128 each) into one 8-byte store.
    unsigned long long pack = 0;
#pragma unroll
    for (int j = 0; j < KPT; ++j)
        pack |= (unsigned long long)(unsigned)cnt[j] << (8 * j);
    *(unsigned long long*)(counts + (size_t)chunk * (TC * NB)
                                  + (size_t)tc * NB + kq * KPT) = pack;
}

__global__ __launch_bounds__(256) void histo_loss_kernel(
    const unsigned char* __restrict__ counts, // [CHUNKS][4096][64]
    const float* __restrict__ deltas,         // [4096]
    const float* __restrict__ dens,           // [4096, 64]
    float* __restrict__ out)                  // [1]
{
    const int i = blockIdx.x * 256 + threadIdx.x;  // item = tc*64 + k

    int cnt = 0;
#pragma unroll
    for (int ch = 0; ch < CHUNKS; ++ch)
        cnt += (int)counts[(size_t)ch * (TC * NB) + i];

    const float delta = deltas[i >> 6];
    // Match reference rounding: (cnt/1024) exact, then divide by delta.
    const float density = (cnt * (1.0f / 1024.0f)) / delta;
    float s = fabsf(density - dens[i]);

#pragma unroll
    for (int off = 32; off > 0; off >>= 1)
        s += __shfl_down(s, off, 64);

    __shared__ float sb[4];
    if ((threadIdx.x & 63) == 0) sb[threadIdx.x >> 6] = s;
    __syncthreads();

    if (threadIdx.x == 0)
        atomicAdd(out, (sb[0] + sb[1] + sb[2] + sb[3]) * (1.0f / 262144.0f));
}

extern "C" void kernel_launch(void* const* d_in, const int* in_sizes, int n_in,
                              void* d_out, int out_size, void* d_ws, size_t ws_size,
                              hipStream_t stream) {
    const float* x      = (const float*)d_in[0];  // x_fake    [1024,256,16]
    const float* locs   = (const float*)d_in[1];  // locs      [256,16,64]
    const float* deltas = (const float*)d_in[2];  // deltas    [256,16]
    const float* dens   = (const float*)d_in[3];  // densities [256,16,64]
    float* out = (float*)d_out;
    unsigned char* cnts = (unsigned char*)d_ws;   // 2 MB of scratch

    histo_count_kernel<<<T_DIM * CHUNKS, 128, 0, stream>>>(x, locs, deltas, cnts, out);
    histo_loss_kernel<<<(TC * NB) / 256, 256, 0, stream>>>(cnts, deltas, dens, out);
}

// Round 3
// 92.896 us; speedup vs baseline: 1.2045x; 1.1148x over previous
//
#include <hip/hip_runtime.h>

// HistoLoss: B=1024, T=256, C=16, NB=64; TC=4096; x flat = [b][tc]
//
// Harness note (round-2 finding): the timed window includes a ~43 us
// 256 MB ws re-poison fill + ~9 us input restores -> ~55 us fixed floor.
// Our job is to get kernel time from ~48 us (round 2) to the ~15 us floor.
//
// k1: block = 128 thr (16 c x 8 kq), one block per (t, 64-b chunk).
//     16 chunks -> grid 4096 -> 16 blocks/CU = 32 waves/CU = 8 waves/SIMD
//     (round 2 ran 4 waves/SIMD and stalled at ~3x the VALU issue floor).
//     Per b: 1 LDS broadcast read + 8x(sub, cmp-abs, addc) VALU. Zero SALU.
//     Counts <=64 -> 8 x u8 packed -> one 8B store per thread.
//     Swizzle t = bidx & 255 (256 % 8 == 0 -> all chunks of a t share an XCD;
//     each 64B x-line read by exactly one block -> x fetch == 16 MiB exact).
// k2: per (tc,k): sum 16 chunk u8s, loss term, block-reduce -> partial store.
// k3: single block reduces 1024 partials -> out[0]. No atomics, no memset,
//     deterministic; every ws byte read is written earlier in this call.

#define T_DIM   256
#define C_DIM   16
#define NB      64
#define TC      4096
#define CHUNKS  16
#define BCH     64             // b per chunk (counts fit u8: <=64)
#define KPT     8              // k per thread

__global__ __launch_bounds__(128, 8) void histo_count_kernel(
    const float* __restrict__ x,       // [1024, 4096]
    const float* __restrict__ locs,    // [4096, 64]
    const float* __restrict__ deltas,  // [4096]
    unsigned char* __restrict__ counts)// [CHUNKS][4096][64] u8
{
    __shared__ float xs[BCH * C_DIM];  // 1024 floats = 4 KB
    const int tid   = threadIdx.x;
    const int t     = blockIdx.x & 255;
    const int chunk = blockIdx.x >> 8;

    // Stage x[chunk*64 .. +63][t*16 .. +15] -> LDS. 2 float4 per thread,
    // 4 consecutive threads cover one 64B row: line-exact fetch.
    const float* xbase = x + (size_t)(chunk * BCH) * TC + t * C_DIM;
#pragma unroll
    for (int p = 0; p < 2; ++p) {
        const int lin = p * 512 + tid * 4;
        const int bi  = lin >> 4;
        const int c4  = lin & 15;
        *(float4*)(xs + lin) = *(const float4*)(xbase + (size_t)bi * TC + c4);
    }

    const int c  = tid >> 3;           // 0..15
    const int kq = tid & 7;            // 0..7 -> k in [kq*8, kq*8+8)
    const int tc = t * C_DIM + c;

    const float h = 0.5f * deltas[tc];
    float lc[KPT];
    const float* lp = locs + (size_t)tc * NB + kq * KPT;
#pragma unroll
    for (int j = 0; j < KPT; ++j) lc[j] = lp[j];

    int cnt[KPT];
#pragma unroll
    for (int j = 0; j < KPT; ++j) cnt[j] = 0;

    __syncthreads();

    // 64 iters x (1 LDS broadcast + 24 VALU). 8 independent j-chains give the
    // scheduler ILP; 8 waves/SIMD give TLP. Conflict-free (8-lane broadcast).
    const float* xc = xs + c;
#pragma unroll 8
    for (int bi = 0; bi < BCH; ++bi) {
        const float xv = xc[bi * C_DIM];
#pragma unroll
        for (int j = 0; j < KPT; ++j)
            cnt[j] += (fabsf(xv - lc[j]) < h) ? 1 : 0;
    }

    unsigned long long pack = 0;
#pragma unroll
    for (int j = 0; j < KPT; ++j)
        pack |= (unsigned long long)(unsigned)cnt[j] << (8 * j);
    *(unsigned long long*)(counts + (size_t)chunk * (TC * NB)
                                  + (size_t)tc * NB + kq * KPT) = pack;
}

__global__ __launch_bounds__(256) void histo_loss_kernel(
    const unsigned char* __restrict__ counts, // [CHUNKS][4096][64]
    const float* __restrict__ deltas,         // [4096]
    const float* __restrict__ dens,           // [4096, 64]
    float* __restrict__ partials)             // [1024]
{
    const int i = blockIdx.x * 256 + threadIdx.x;  // item = tc*64 + k

    int cnt = 0;
#pragma unroll
    for (int ch = 0; ch < CHUNKS; ++ch)
        cnt += (int)counts[(size_t)ch * (TC * NB) + i];

    const float delta = deltas[i >> 6];
    // Match reference order: (cnt/1024) exact, then / delta.
    const float density = (cnt * (1.0f / 1024.0f)) / delta;
    float s = fabsf(density - dens[i]);

#pragma unroll
    for (int off = 32; off > 0; off >>= 1)
        s += __shfl_down(s, off, 64);

    __shared__ float sb[4];
    if ((threadIdx.x & 63) == 0) sb[threadIdx.x >> 6] = s;
    __syncthreads();

    if (threadIdx.x == 0)
        partials[blockIdx.x] = sb[0] + sb[1] + sb[2] + sb[3];
}

__global__ __launch_bounds__(256) void histo_final_kernel(
    const float* __restrict__ partials,  // [1024]
    float* __restrict__ out)             // [1]
{
    const int tid = threadIdx.x;
    float s = 0.0f;
#pragma unroll
    for (int i = 0; i < 4; ++i)
        s += partials[tid + i * 256];

#pragma unroll
    for (int off = 32; off > 0; off >>= 1)
        s += __shfl_down(s, off, 64);

    __shared__ float sb[4];
    if ((tid & 63) == 0) sb[tid >> 6] = s;
    __syncthreads();

    if (tid == 0)  // REG * mean over (t,c,k) = sum / 262144
        out[0] = (sb[0] + sb[1] + sb[2] + sb[3]) * (1.0f / 262144.0f);
}

extern "C" void kernel_launch(void* const* d_in, const int* in_sizes, int n_in,
                              void* d_out, int out_size, void* d_ws, size_t ws_size,
                              hipStream_t stream) {
    const float* x      = (const float*)d_in[0];  // x_fake    [1024,256,16]
    const float* locs   = (const float*)d_in[1];  // locs      [256,16,64]
    const float* deltas = (const float*)d_in[2];  // deltas    [256,16]
    const float* dens   = (const float*)d_in[3];  // densities [256,16,64]
    float* out = (float*)d_out;

    unsigned char* cnts = (unsigned char*)d_ws;                    // 4 MB
    float* partials     = (float*)((char*)d_ws + (size_t)CHUNKS * TC * NB); // 4 KB

    histo_count_kernel<<<T_DIM * CHUNKS, 128, 0, stream>>>(x, locs, deltas, cnts);
    histo_loss_kernel<<<(TC * NB) / 256, 256, 0, stream>>>(cnts, deltas, dens, partials);
    histo_final_kernel<<<1, 256, 0, stream>>>(partials, out);
}